// Round 4
// baseline (380.423 us; speedup 1.0000x reference)
//
#include <hip/hip_runtime.h>
#include <cstdint>

#define NPATH 131072
#define TPTS  500
#define NSTEP (TPTS - 1)
#define HID   64
#define BLOCK 256
// two threads per path: role 0 = drift MLP, role 1 = diffusion MLP
#define NTHREADS (2 * NPATH)

// K = 2*log2(e): tanh(a) = 1 - 2 / (2^(K*a) + 1)   (exact identity)
#define K2LOG2E 2.8853900817779268f

__device__ __forceinline__ float fexp2(float x) { return __builtin_amdgcn_exp2f(x); }
__device__ __forceinline__ float frcp(float x)  { return __builtin_amdgcn_rcpf(x); }

// one single-active-term tanh MLP with pre-scaled constants:
//   e = 2^(w1*y + b1); r = 1/(e+1); a = w2t*r + D; out = 1 - 2/(2^a + 1)
__device__ __forceinline__ float mlp1(float y, float w1, float b1, float w2t, float D)
{
    float e  = fexp2(fmaf(w1, y, b1));
    float r  = frcp(e + 1.0f);
    float a  = fmaf(w2t, r, D);
    float r2 = frcp(fexp2(a) + 1.0f);
    return fmaf(-2.0f, r2, 1.0f);
}

// One Euler-Maruyama step, 2-lane version. Each lane evaluates ONE MLP
// (constants differ per role), partner value comes via shfl_xor. Both lanes
// then perform the identical y-update in the identical order -> y stays
// bit-identical across the lane pair (numerics == the 1-thread version).
__device__ __forceinline__ float step2(float y, float dt, float sdt, float z, bool role,
                                       float w1, float b1, float w2t, float D)
{
    float zdt    = sdt * z;                    // off the critical y-chain
    float mine   = mlp1(y, w1, b1, w2t, D);
    float theirs = __shfl_xor(mine, 1, 64);
    float fv = role ? theirs : mine;
    float gv = role ? mine   : theirs;
    y = fmaf(fv, dt, y);
    return fmaf(gv, zdt, y);
}

__global__ __launch_bounds__(BLOCK, 4) void deepsde_kernel(
    const float* __restrict__ y0,
    const float* __restrict__ times,
    const float* __restrict__ noise,
    const float* __restrict__ f1_w, const float* __restrict__ f1_b,
    const float* __restrict__ f2_w, const float* __restrict__ f2_b,
    const float* __restrict__ g1_w, const float* __restrict__ g1_b,
    const float* __restrict__ g2_w, const float* __restrict__ g2_b,
    float* __restrict__ out)
{
    __shared__ float2 s_dt[NSTEP];          // (dt, sqrt(dt)) per step  (~4 KB)
    __shared__ float  s_w1p[2][HID], s_b1p[2][HID], s_w2t[2][HID];
    __shared__ float  s_D[2];
    __shared__ int    s_n[2];

    const int tid = threadIdx.x;

    // dt table into LDS (uniform across blocks; times is 500 floats, L2-hot)
    for (int t = tid; t < NSTEP; t += BLOCK) {
        float dt = times[t + 1] - times[t];
        s_dt[t] = make_float2(dt, sqrtf(dt));
    }

    // Weight preprocessing: wave 0 -> f-MLP, wave 1 -> g-MLP.
    // Fold all w1==0 terms into a constant; keep active terms (pre-scaled by K).
    if (tid < 128) {
        const int which = tid >> 6;   // 0=f, 1=g
        const int lane  = tid & 63;
        const float* w1 = which ? g1_w : f1_w;
        const float* b1 = which ? g1_b : f1_b;
        const float* w2 = which ? g2_w : f2_w;
        const float* b2 = which ? g2_b : f2_b;
        float w1v = w1[lane];
        float b1v = b1[lane];
        float w2v = w2[lane];
        bool active = (w1v != 0.0f);
        unsigned long long mask = __ballot(active);
        float csum = active ? 0.0f : w2v * tanhf(b1v);   // constant contribution
        float asum = active ? w2v : 0.0f;                // sum of active w2
        for (int off = 32; off > 0; off >>= 1) {
            csum += __shfl_down(csum, off);
            asum += __shfl_down(asum, off);
        }
        if (lane == 0) {
            s_n[which] = __popcll(mask);
            s_D[which] = K2LOG2E * (csum + b2[0] + asum);
        }
        if (active) {
            int rank = __popcll(mask & ((1ull << lane) - 1ull));
            s_w1p[which][rank] = K2LOG2E * w1v;
            s_b1p[which][rank] = K2LOG2E * b1v;
            s_w2t[which][rank] = -2.0f * K2LOG2E * w2v;
        }
    }
    __syncthreads();

    const bool role = tid & 1;                           // 0=f, 1=g
    const int  p    = blockIdx.x * (BLOCK / 2) + (tid >> 1);   // path index
    const int  nf = s_n[0], ng = s_n[1];

    float y = y0[p];
    const float yinit = y;

    if (nf == 1 && ng == 1) {
        // ---- fast path: single active term per MLP (the given inputs) ----
        // per-role constant selection (wave-uniform LDS broadcasts + cndmask)
        const float fw1 = s_w1p[0][0], fb1 = s_b1p[0][0], fw2 = s_w2t[0][0], fDv = s_D[0];
        const float gw1 = s_w1p[1][0], gb1 = s_b1p[1][0], gw2 = s_w2t[1][0], gDv = s_D[1];
        const float w1  = role ? gw1 : fw1;
        const float b1  = role ? gb1 : fb1;
        const float w2t = role ? gw2 : fw2;
        const float D   = role ? gDv : fDv;

        const float* np = noise + p;

        // 8-deep register prefetch. 4 waves/SIMD now; in-flight bytes/SIMD =
        // 4 waves * 64 lanes * 8 * 4B (pairs share lines) -> ample latency
        // tolerance for the 6.3 TB/s stream.
        float z0 = np[0 * NPATH];
        float z1 = np[1 * NPATH];
        float z2 = np[2 * NPATH];
        float z3 = np[3 * NPATH];
        float z4 = np[4 * NPATH];
        float z5 = np[5 * NPATH];
        float z6 = np[6 * NPATH];
        float z7 = np[7 * NPATH];

        int t = 0;
        for (; t + 15 < NSTEP; t += 8) {
            const float* pp = np + (size_t)(t + 8) * NPATH;
            float n0 = pp[0 * NPATH];
            float n1 = pp[1 * NPATH];
            float n2 = pp[2 * NPATH];
            float n3 = pp[3 * NPATH];
            float n4 = pp[4 * NPATH];
            float n5 = pp[5 * NPATH];
            float n6 = pp[6 * NPATH];
            float n7 = pp[7 * NPATH];
            float2 d0 = s_dt[t],     d1 = s_dt[t + 1], d2 = s_dt[t + 2], d3 = s_dt[t + 3];
            float2 d4 = s_dt[t + 4], d5 = s_dt[t + 5], d6 = s_dt[t + 6], d7 = s_dt[t + 7];
            y = step2(y, d0.x, d0.y, z0, role, w1, b1, w2t, D);
            y = step2(y, d1.x, d1.y, z1, role, w1, b1, w2t, D);
            y = step2(y, d2.x, d2.y, z2, role, w1, b1, w2t, D);
            y = step2(y, d3.x, d3.y, z3, role, w1, b1, w2t, D);
            y = step2(y, d4.x, d4.y, z4, role, w1, b1, w2t, D);
            y = step2(y, d5.x, d5.y, z5, role, w1, b1, w2t, D);
            y = step2(y, d6.x, d6.y, z6, role, w1, b1, w2t, D);
            y = step2(y, d7.x, d7.y, z7, role, w1, b1, w2t, D);
            z0 = n0; z1 = n1; z2 = n2; z3 = n3;
            z4 = n4; z5 = n5; z6 = n6; z7 = n7;
        }
        // loop exits with t == 488: 8 buffered steps (488..495), then 3 direct
        {
            float2 d0 = s_dt[t],     d1 = s_dt[t + 1], d2 = s_dt[t + 2], d3 = s_dt[t + 3];
            float2 d4 = s_dt[t + 4], d5 = s_dt[t + 5], d6 = s_dt[t + 6], d7 = s_dt[t + 7];
            y = step2(y, d0.x, d0.y, z0, role, w1, b1, w2t, D);
            y = step2(y, d1.x, d1.y, z1, role, w1, b1, w2t, D);
            y = step2(y, d2.x, d2.y, z2, role, w1, b1, w2t, D);
            y = step2(y, d3.x, d3.y, z3, role, w1, b1, w2t, D);
            y = step2(y, d4.x, d4.y, z4, role, w1, b1, w2t, D);
            y = step2(y, d5.x, d5.y, z5, role, w1, b1, w2t, D);
            y = step2(y, d6.x, d6.y, z6, role, w1, b1, w2t, D);
            y = step2(y, d7.x, d7.y, z7, role, w1, b1, w2t, D);
        }
        for (t += 8; t < NSTEP; ++t) {
            float z = np[(size_t)t * NPATH];
            float2 d = s_dt[t];
            y = step2(y, d.x, d.y, z, role, w1, b1, w2t, D);
        }
    } else {
        // ---- general path (correctness fallback, never hot): role-0 lane
        // of each pair computes the full step with loops over active terms.
        if (!role) {
            const float fD = s_D[0], gD = s_D[1];
            for (int t = 0; t < NSTEP; ++t) {
                float z = noise[(size_t)t * NPATH + p];
                float2 d = s_dt[t];
                float af = fD;
                for (int k = 0; k < nf; ++k) {
                    float e = fexp2(fmaf(s_w1p[0][k], y, s_b1p[0][k]));
                    float r = frcp(e + 1.0f);
                    af = fmaf(s_w2t[0][k], r, af);
                }
                float fv = fmaf(-2.0f, frcp(fexp2(af) + 1.0f), 1.0f);
                float ag = gD;
                for (int k = 0; k < ng; ++k) {
                    float e = fexp2(fmaf(s_w1p[1][k], y, s_b1p[1][k]));
                    float r = frcp(e + 1.0f);
                    ag = fmaf(s_w2t[1][k], r, ag);
                }
                float gv = fmaf(-2.0f, frcp(fexp2(ag) + 1.0f), 1.0f);
                y = fmaf(fv, d.x, y);
                y = fmaf(gv, d.y * z, y);
            }
        }
    }

    if (!role) out[p] = logf(y / yinit);
}

extern "C" void kernel_launch(void* const* d_in, const int* in_sizes, int n_in,
                              void* d_out, int out_size, void* d_ws, size_t ws_size,
                              hipStream_t stream)
{
    const float* y0    = (const float*)d_in[0];
    const float* times = (const float*)d_in[1];
    const float* noise = (const float*)d_in[2];
    const float* f1_w  = (const float*)d_in[3];
    const float* f1_b  = (const float*)d_in[4];
    const float* f2_w  = (const float*)d_in[5];
    const float* f2_b  = (const float*)d_in[6];
    const float* g1_w  = (const float*)d_in[7];
    const float* g1_b  = (const float*)d_in[8];
    const float* g2_w  = (const float*)d_in[9];
    const float* g2_b  = (const float*)d_in[10];
    float* out = (float*)d_out;

    deepsde_kernel<<<NTHREADS / BLOCK, BLOCK, 0, stream>>>(
        y0, times, noise,
        f1_w, f1_b, f2_w, f2_b,
        g1_w, g1_b, g2_w, g2_b,
        out);
}

// Round 5
// 375.179 us; speedup vs baseline: 1.0140x; 1.0140x over previous
//
#include <hip/hip_runtime.h>
#include <cstdint>

#define NPATH 131072
#define TPTS  500
#define NSTEP (TPTS - 1)
#define HID   64
#define BLOCK 256

// K = 2*log2(e): tanh(a) = 1 - 2 / (2^(K*a) + 1)   (exact identity)
#define K2LOG2E 2.8853900817779268f

__device__ __forceinline__ float fexp2(float x) { return __builtin_amdgcn_exp2f(x); }
__device__ __forceinline__ float frcp(float x)  { return __builtin_amdgcn_rcpf(x); }

// One Euler-Maruyama step, fast path (1 active term per MLP), zdt = sqrt(dt)*z
// pre-multiplied at promotion time (off the critical chain).
__device__ __forceinline__ float sde_step(float y, float dt, float zdt,
                                          float fw1, float fb1, float fw2, float fD,
                                          float gw1, float gb1, float gw2, float gD)
{
    // drift MLP: tanh(tanh(.)) via 2^x identity
    float ef  = fexp2(fmaf(fw1, y, fb1));
    float rf  = frcp(ef + 1.0f);
    float af  = fmaf(fw2, rf, fD);
    float r2f = frcp(fexp2(af) + 1.0f);
    float fv  = fmaf(-2.0f, r2f, 1.0f);
    // diffusion MLP (independent chain -> ILP with drift chain)
    float eg  = fexp2(fmaf(gw1, y, gb1));
    float rg  = frcp(eg + 1.0f);
    float ag  = fmaf(gw2, rg, gD);
    float r2g = frcp(fexp2(ag) + 1.0f);
    float gv  = fmaf(-2.0f, r2g, 1.0f);

    y = fmaf(fv, dt, y);
    return fmaf(gv, zdt, y);
}

__global__ __launch_bounds__(BLOCK) void deepsde_kernel(
    const float* __restrict__ y0,
    const float* __restrict__ times,
    const float* __restrict__ noise,
    const float* __restrict__ f1_w, const float* __restrict__ f1_b,
    const float* __restrict__ f2_w, const float* __restrict__ f2_b,
    const float* __restrict__ g1_w, const float* __restrict__ g1_b,
    const float* __restrict__ g2_w, const float* __restrict__ g2_b,
    float* __restrict__ out)
{
    __shared__ float2 s_dt[NSTEP];          // (dt, sqrt(dt)) per step  (~4 KB)
    __shared__ float  s_w1p[2][HID], s_b1p[2][HID], s_w2t[2][HID];
    __shared__ float  s_D[2];
    __shared__ int    s_n[2];

    const int tid = threadIdx.x;

    // dt table into LDS (uniform across blocks; times is 500 floats, L2-hot)
    for (int t = tid; t < NSTEP; t += BLOCK) {
        float dt = times[t + 1] - times[t];
        s_dt[t] = make_float2(dt, sqrtf(dt));
    }

    // Weight preprocessing: wave 0 -> f-MLP, wave 1 -> g-MLP.
    // Fold all w1==0 terms into a constant; keep active terms (pre-scaled by K).
    if (tid < 128) {
        const int which = tid >> 6;   // 0=f, 1=g
        const int lane  = tid & 63;
        const float* w1 = which ? g1_w : f1_w;
        const float* b1 = which ? g1_b : f1_b;
        const float* w2 = which ? g2_w : f2_w;
        const float* b2 = which ? g2_b : f2_b;
        float w1v = w1[lane];
        float b1v = b1[lane];
        float w2v = w2[lane];
        bool active = (w1v != 0.0f);
        unsigned long long mask = __ballot(active);
        float csum = active ? 0.0f : w2v * tanhf(b1v);   // constant contribution
        float asum = active ? w2v : 0.0f;                // sum of active w2
        for (int off = 32; off > 0; off >>= 1) {
            csum += __shfl_down(csum, off);
            asum += __shfl_down(asum, off);
        }
        if (lane == 0) {
            s_n[which] = __popcll(mask);
            s_D[which] = K2LOG2E * (csum + b2[0] + asum);
        }
        if (active) {
            int rank = __popcll(mask & ((1ull << lane) - 1ull));
            s_w1p[which][rank] = K2LOG2E * w1v;
            s_b1p[which][rank] = K2LOG2E * b1v;
            s_w2t[which][rank] = -2.0f * K2LOG2E * w2v;
        }
    }
    __syncthreads();

    const int i = blockIdx.x * BLOCK + tid;
    const int nf = s_n[0], ng = s_n[1];
    const float fD = s_D[0], gD = s_D[1];

    float y = y0[i];
    const float yinit = y;

    if (nf == 1 && ng == 1) {
        // ---- fast path: single active term per MLP (the given inputs) ----
        const float fw1 = s_w1p[0][0], fb1 = s_b1p[0][0], fw2 = s_w2t[0][0];
        const float gw1 = s_w1p[1][0], gb1 = s_b1p[1][0], gw2 = s_w2t[1][0];

        const float* np = noise + i;

        // 16-deep register prefetch. Little's law: 6.3 TB/s at ~2000cy loaded
        // latency needs ~20.5 KB/CU in flight; 8 waves/CU * 16 loads * 256 B
        // = 32 KB/CU clears it (8-deep = 16 KB did not -> ~5 TB/s cap).
        // z holds sqrt(dt)*noise, pre-multiplied at promotion (off hot chain).
#define PRO(k) float z##k = np[(k) * NPATH] * s_dt[k].y;
        PRO(0) PRO(1) PRO(2) PRO(3) PRO(4) PRO(5) PRO(6) PRO(7)
        PRO(8) PRO(9) PRO(10) PRO(11) PRO(12) PRO(13) PRO(14) PRO(15)
#undef PRO

        int t = 0;
        for (; t + 31 < NSTEP; t += 16) {
            const float* pp = np + (size_t)(t + 16) * NPATH;
#define LOADN(k)  float n##k = pp[(k) * NPATH];
#define STEPK(k)  y = sde_step(y, s_dt[t + (k)].x, z##k, fw1, fb1, fw2, fD, gw1, gb1, gw2, gD);
#define PROM(k)   z##k = n##k * s_dt[t + 16 + (k)].y;
            LOADN(0) LOADN(1) LOADN(2) LOADN(3) LOADN(4) LOADN(5) LOADN(6) LOADN(7)
            LOADN(8) LOADN(9) LOADN(10) LOADN(11) LOADN(12) LOADN(13) LOADN(14) LOADN(15)
            STEPK(0) STEPK(1) STEPK(2) STEPK(3) STEPK(4) STEPK(5) STEPK(6) STEPK(7)
            STEPK(8) STEPK(9) STEPK(10) STEPK(11) STEPK(12) STEPK(13) STEPK(14) STEPK(15)
            PROM(0) PROM(1) PROM(2) PROM(3) PROM(4) PROM(5) PROM(6) PROM(7)
            PROM(8) PROM(9) PROM(10) PROM(11) PROM(12) PROM(13) PROM(14) PROM(15)
#undef LOADN
#undef PROM
        }
        // loop exits with t == 480: 16 buffered steps (480..495), then 3 direct
        {
            STEPK(0) STEPK(1) STEPK(2) STEPK(3) STEPK(4) STEPK(5) STEPK(6) STEPK(7)
            STEPK(8) STEPK(9) STEPK(10) STEPK(11) STEPK(12) STEPK(13) STEPK(14) STEPK(15)
        }
#undef STEPK
        for (t += 16; t < NSTEP; ++t) {
            float zdt = np[(size_t)t * NPATH] * s_dt[t].y;
            y = sde_step(y, s_dt[t].x, zdt, fw1, fb1, fw2, fD, gw1, gb1, gw2, gD);
        }
    } else {
        // ---- general path: loop over active terms (correctness fallback) ----
        for (int t = 0; t < NSTEP; ++t) {
            float z = noise[(size_t)t * NPATH + i];
            float2 d = s_dt[t];
            float af = fD;
            for (int k = 0; k < nf; ++k) {
                float e = fexp2(fmaf(s_w1p[0][k], y, s_b1p[0][k]));
                float r = frcp(e + 1.0f);
                af = fmaf(s_w2t[0][k], r, af);
            }
            float fv = fmaf(-2.0f, frcp(fexp2(af) + 1.0f), 1.0f);
            float ag = gD;
            for (int k = 0; k < ng; ++k) {
                float e = fexp2(fmaf(s_w1p[1][k], y, s_b1p[1][k]));
                float r = frcp(e + 1.0f);
                ag = fmaf(s_w2t[1][k], r, ag);
            }
            float gv = fmaf(-2.0f, frcp(fexp2(ag) + 1.0f), 1.0f);
            y = fmaf(fv, d.x, y);
            y = fmaf(gv, d.y * z, y);
        }
    }

    out[i] = logf(y / yinit);
}

extern "C" void kernel_launch(void* const* d_in, const int* in_sizes, int n_in,
                              void* d_out, int out_size, void* d_ws, size_t ws_size,
                              hipStream_t stream)
{
    const float* y0    = (const float*)d_in[0];
    const float* times = (const float*)d_in[1];
    const float* noise = (const float*)d_in[2];
    const float* f1_w  = (const float*)d_in[3];
    const float* f1_b  = (const float*)d_in[4];
    const float* f2_w  = (const float*)d_in[5];
    const float* f2_b  = (const float*)d_in[6];
    const float* g1_w  = (const float*)d_in[7];
    const float* g1_b  = (const float*)d_in[8];
    const float* g2_w  = (const float*)d_in[9];
    const float* g2_b  = (const float*)d_in[10];
    float* out = (float*)d_out;

    deepsde_kernel<<<NPATH / BLOCK, BLOCK, 0, stream>>>(
        y0, times, noise,
        f1_w, f1_b, f2_w, f2_b,
        g1_w, g1_b, g2_w, g2_b,
        out);
}